// Round 8
// baseline (196.716 us; speedup 1.0000x reference)
//
#include <hip/hip_runtime.h>

#define BB 2
#define SS 4096
#define EE 768
#define HH 12
#define DD 64
#define WW 256

typedef __attribute__((ext_vector_type(8))) short short8;
typedef __attribute__((ext_vector_type(4))) short short4v;
typedef __attribute__((ext_vector_type(4))) float floatx4;

#define MFMA16(a, b, c) __builtin_amdgcn_mfma_f32_16x16x32_bf16(a, b, c, 0, 0, 0)

__device__ __forceinline__ float bf2f(short x) {
    union { unsigned u; float f; } v;
    v.u = ((unsigned)(unsigned short)x) << 16;
    return v.f;
}

__device__ __forceinline__ short f2bf(float x) {
    union { float f; unsigned u; } v;
    v.f = x;
    unsigned r = v.u + 0x7fffu + ((v.u >> 16) & 1u);  // RNE
    return (short)(r >> 16);
}

__device__ __forceinline__ int imin(int a, int b) { return a < b ? a : b; }
__device__ __forceinline__ int imax(int a, int b) { return a > b ? a : b; }

// async global->LDS, 16B per lane; LDS dest must be wave-uniform-base + lane*16
__device__ __forceinline__ void gload_lds16(const short* g, short* l) {
    __builtin_amdgcn_global_load_lds(
        (const __attribute__((address_space(1))) unsigned*)g,
        (__attribute__((address_space(3))) unsigned*)l, 16, 0, 0);
}

// Fused prep: blocks [0,3072) convert X fp32->bf16 (8 el/thread);
// blocks [3072,4800) transpose the three 768x768 weights to bf16 Wt[z][n][k].
__global__ __launch_bounds__(256) void prep(
    const float* __restrict__ hidden, const float* __restrict__ W0,
    const float* __restrict__ W1, const float* __restrict__ W2,
    short* __restrict__ Xb, short* __restrict__ Wt) {
    __shared__ short t[32][33];
    int bid = blockIdx.x;
    if (bid < 3072) {
        int i = bid * 256 + threadIdx.x;
        const floatx4* src = (const floatx4*)(hidden + (size_t)i * 8);
        floatx4 f0 = src[0], f1 = src[1];
        short8 s8;
#pragma unroll
        for (int j = 0; j < 4; j++) { s8[j] = f2bf(f0[j]); s8[j + 4] = f2bf(f1[j]); }
        *(short8*)(Xb + (size_t)i * 8) = s8;
    } else {
        int tmp = bid - 3072;
        int z = tmp / 576, r = tmp % 576;
        int bx = r % 24, by = r / 24;
        const float* in = (z == 0) ? W0 : (z == 1) ? W1 : W2;
        short* op = Wt + (size_t)z * EE * EE;
        int tx = threadIdx.x & 31, ty = threadIdx.x >> 5;  // 32 x 8
        int x = bx * 32 + tx, y0 = by * 32;
        for (int j = 0; j < 32; j += 8) t[ty + j][tx] = f2bf(in[(size_t)(y0 + ty + j) * EE + x]);
        __syncthreads();
        int x2 = y0 + tx, y2 = bx * 32;
        for (int j = 0; j < 32; j += 8) op[(size_t)(y2 + ty + j) * EE + x2] = t[tx][ty + j];
    }
}

// Barrier-free wave-tile GEMM: one wave per 64x64 output tile, wave-private
// double-buffered LDS, global_load_lds staging with fine-grained
// s_waitcnt vmcnt(8) (prefetch stays in flight; never drains to 0 mid-loop).
// Grid (m=128, n=12, z=3): consecutive block ids vary m -> the 36 readers of
// one A-slab land on the same XCD (ids equal mod 128); A slabs stay in that
// XCD's L2 (12.6/8 = 1.6 MB), Wt (3.5 MB) is L2-resident everywhere.
// z=0: Q*(1/8) -> [B,H,S,D];  z=1: K -> [B,H,S,D];  z=2: V -> [B,H,D,S]
__global__ __launch_bounds__(64) void qkv_gemm(
    const short* __restrict__ Xb, const short* __restrict__ Wt,
    const float* __restrict__ Bq, const float* __restrict__ Bk, const float* __restrict__ Bv,
    short* __restrict__ Qo, short* __restrict__ Ko, short* __restrict__ Vto) {
    int z = blockIdx.z;
    const short* Wz = Wt + (size_t)z * EE * EE;
    const float* bias = (z == 0) ? Bq : (z == 1) ? Bk : Bv;

    __shared__ __align__(16) short As[2][64 * 32];  // 8 KB
    __shared__ __align__(16) short Bs[2][64 * 32];  // 8 KB
    int lane = threadIdx.x;
    int m0 = blockIdx.x * 64, n0 = blockIdx.y * 64;
    int lquad = lane >> 4, lrow = lane & 15;

    floatx4 acc[4][4] = {};

    // staging: chunk c = j*64 + lane (j=0..3); row = c>>2, col = (c&3)*8
    auto stage = [&](int k0, int buf) {
#pragma unroll
        for (int j = 0; j < 4; j++) {
            int c = j * 64 + lane;
            int row = c >> 2, col = (c & 3) * 8;
            gload_lds16(&Xb[(size_t)(m0 + row) * EE + k0 + col], &As[buf][c * 8]);
            gload_lds16(&Wz[(size_t)(n0 + row) * EE + k0 + col], &Bs[buf][c * 8]);
        }
    };

    stage(0, 0);
    for (int i = 0; i < 24; i++) {
        int buf = i & 1;
        if (i < 23) {
            stage((i + 1) * 32, buf ^ 1);
            // wait for tile i's 8 loads; tile i+1's 8 stay in flight
            asm volatile("s_waitcnt vmcnt(8)" ::: "memory");
        } else {
            asm volatile("s_waitcnt vmcnt(0)" ::: "memory");
        }
        short8 af[4], bfv[4];
#pragma unroll
        for (int mt = 0; mt < 4; mt++)
            af[mt] = *(short8*)&As[buf][(mt * 16 + lrow) * 32 + lquad * 8];
#pragma unroll
        for (int nt = 0; nt < 4; nt++)
            bfv[nt] = *(short8*)&Bs[buf][(nt * 16 + lrow) * 32 + lquad * 8];
#pragma unroll
        for (int mt = 0; mt < 4; mt++)
#pragma unroll
            for (int nt = 0; nt < 4; nt++)
                acc[mt][nt] = MFMA16(af[mt], bfv[nt], acc[mt][nt]);
    }

    if (z == 2) {
        // V, stored transposed: Vt[b,h,d,s]
        for (int nt = 0; nt < 4; nt++) {
            int gn = n0 + nt * 16 + lrow;
            float bv = bias[gn];
            int h = gn >> 6, d = gn & 63;
            for (int mt = 0; mt < 4; mt++) {
                int gm0 = m0 + mt * 16 + lquad * 4;  // multiple of 4
                int b = gm0 >> 12, s = gm0 & (SS - 1);
                short4v pk;
                for (int r = 0; r < 4; r++) pk[r] = f2bf(acc[mt][nt][r] + bv);
                *(short4v*)&Vto[(((size_t)(b * HH + h)) * DD + d) * SS + s] = pk;
            }
        }
    } else {
        short* out = (z == 0) ? Qo : Ko;
        float scale = (z == 0) ? 0.125f : 1.0f;
        for (int nt = 0; nt < 4; nt++) {
            int gn = n0 + nt * 16 + lrow;
            float bv = bias[gn];
            int h = gn >> 6, d = gn & 63;
            for (int mt = 0; mt < 4; mt++) {
                int gmb = m0 + mt * 16 + lquad * 4;
                for (int r = 0; r < 4; r++) {
                    int gm = gmb + r;
                    int b = gm >> 12, s = gm & (SS - 1);
                    float v = (acc[mt][nt][r] + bv) * scale;
                    out[(((size_t)(b * HH + h)) * SS + s) * DD + d] = f2bf(v);
                }
            }
        }
    }
}

// Sliding-window attention v3: 128 queries/block (4 waves x 32 queries).
// Grid (hb=24, chunk=32): consecutive chunks differ by 24 blocks = 0 mod 8
// -> same XCD -> a head's K/V stays resident in that XCD's L2.
// S^T = K*Q^T trick. Q,K bf16 [B,H,S,D]; Vt bf16 [B,H,D,S]; out fp32.
__global__ __launch_bounds__(256) void band_attn(
    const short* __restrict__ Q, const short* __restrict__ K,
    const short* __restrict__ Vt, float* __restrict__ out) {
    int hb = blockIdx.x;  // 0..23
    int h = hb % HH, b = hb / HH;
    int chunk = blockIdx.y;  // 0..31, 128 queries
    int tid = threadIdx.x;
    int wave = tid >> 6, lane = tid & 63, lquad = lane >> 4, lrow = lane & 15;
    int qbase = chunk * 128 + wave * 32;  // this wave's 32 queries

    const short* Qh = Q + ((size_t)(b * HH + h)) * SS * DD;
    const short* Kh = K + ((size_t)(b * HH + h)) * SS * DD;
    const short* Vh = Vt + ((size_t)(b * HH + h)) * DD * SS;

    __shared__ __align__(16) short Ks[64 * 72];     // [key][d]
    __shared__ __align__(16) short Vs[64 * 72];     // [d][key]
    __shared__ __align__(16) short Ps[4][16 * 72];  // per wave: [q][key]
    short* Pw = &Ps[wave][0];

    // Persistent Q B-fragments for 2 m-tiles: B[n=query=lrow][k=d=lquad*8+j]
    short8 qf[2][2];
#pragma unroll
    for (int m = 0; m < 2; m++)
#pragma unroll
        for (int hh = 0; hh < 2; hh++)
            qf[m][hh] = *(const short8*)&Qh[(size_t)(qbase + m * 16 + lrow) * DD + hh * 32 + lquad * 8];

    floatx4 o[2][4] = {};
    float ls[2] = {0.0f, 0.0f};

    int kwin = chunk * 128 - WW;  // block's key-window start (10 tiles of 64)
    int srow = tid >> 3;          // 0..31
    int scol = (tid & 7) * 8;     // 0..56
    int tlo = wave >> 1;          // wave active on tiles [tlo, tlo+9)

    for (int t = 0; t < 10; t++) {
        int ks0 = kwin + t * 64;
        // --- stage K tile [64 keys x 64 d] and Vt tile [64 d x 64 keys] ---
#pragma unroll
        for (int i = 0; i < 2; i++) {
            int r = srow + i * 32;
            int gk = imin(imax(ks0 + r, 0), SS - 1);
            *(short8*)&Ks[r * 72 + scol] = *(const short8*)&Kh[(size_t)gk * DD + scol];
            int gv = imin(imax(ks0 + scol, 0), SS - 8);
            *(short8*)&Vs[r * 72 + scol] = *(const short8*)&Vh[(size_t)r * SS + gv];
        }
        __syncthreads();

        if ((unsigned)(t - tlo) < 9u) {  // this wave's 544-key window
            short8 kf[4][2], vf[4][2];
#pragma unroll
            for (int kt = 0; kt < 4; kt++)
#pragma unroll
                for (int hh = 0; hh < 2; hh++)
                    kf[kt][hh] = *(short8*)&Ks[(kt * 16 + lrow) * 72 + hh * 32 + lquad * 8];
#pragma unroll
            for (int nt = 0; nt < 4; nt++)
#pragma unroll
                for (int hh = 0; hh < 2; hh++)
                    vf[nt][hh] = *(short8*)&Vs[(nt * 16 + lrow) * 72 + hh * 32 + lquad * 8];

#pragma unroll
            for (int m = 0; m < 2; m++) {
                int q = qbase + m * 16 + lrow;  // this lane's query (S^T: col = lane&15)
                floatx4 s[4];
#pragma unroll
                for (int kt = 0; kt < 4; kt++) {
                    floatx4 zz = {};
                    s[kt] = MFMA16(kf[kt][0], qf[m][0], zz);
                    s[kt] = MFMA16(kf[kt][1], qf[m][1], s[kt]);
                }
                float lacc = 0.0f;
#pragma unroll
                for (int kt = 0; kt < 4; kt++) {
                    short4v pk;
#pragma unroll
                    for (int r = 0; r < 4; r++) {
                        int key = ks0 + kt * 16 + lquad * 4 + r;
                        bool valid = ((unsigned)(key - q + WW) <= 2u * WW) && ((unsigned)key < SS);
                        float p = valid ? __expf(s[kt][r]) : 0.0f;
                        pk[r] = f2bf(p);
                        lacc += bf2f(pk[r]);
                    }
                    // 4 consecutive keys for query lrow: one packed 8B store
                    *(short4v*)&Pw[lrow * 72 + kt * 16 + lquad * 4] = pk;
                }
                ls[m] += lacc;
                asm volatile("" ::: "memory");  // order P write->read (same-wave DS is in-order)
                short8 ap0 = *(short8*)&Pw[lrow * 72 + lquad * 8];
                short8 ap1 = *(short8*)&Pw[lrow * 72 + 32 + lquad * 8];
#pragma unroll
                for (int nt = 0; nt < 4; nt++) {
                    o[m][nt] = MFMA16(ap0, vf[nt][0], o[m][nt]);
                    o[m][nt] = MFMA16(ap1, vf[nt][1], o[m][nt]);
                }
            }
        }
        __syncthreads();
    }

    // ls[m]: per-lane partials over this lane's quad; reduce across quads
#pragma unroll
    for (int m = 0; m < 2; m++) {
        ls[m] += __shfl_xor(ls[m], 16, 64);
        ls[m] += __shfl_xor(ls[m], 32, 64);
        ls[m] = 1.0f / ls[m];  // lane L holds 1/ls for query (L&15)
    }

#pragma unroll
    for (int m = 0; m < 2; m++) {
#pragma unroll
        for (int r = 0; r < 4; r++) {
            float linv = __shfl(ls[m], lquad * 4 + r, 64);
            int s = qbase + m * 16 + lquad * 4 + r;
#pragma unroll
            for (int nt = 0; nt < 4; nt++)
                out[((size_t)b * SS + s) * EE + h * DD + nt * 16 + lrow] = o[m][nt][r] * linv;
        }
    }
}

extern "C" void kernel_launch(void* const* d_in, const int* in_sizes, int n_in,
                              void* d_out, int out_size, void* d_ws, size_t ws_size,
                              hipStream_t stream) {
    const float* hidden = (const float*)d_in[0];
    const float* Wq = (const float*)d_in[1];
    const float* bq = (const float*)d_in[2];
    const float* Wk = (const float*)d_in[3];
    const float* bk = (const float*)d_in[4];
    const float* Wv = (const float*)d_in[5];
    const float* bv = (const float*)d_in[6];
    float* out = (float*)d_out;

    short* ws = (short*)d_ws;
    const size_t WSZ = (size_t)EE * EE;            // 589824
    const size_t QSZ = (size_t)BB * HH * SS * DD;  // 6291456
    short* Wt = ws;              // 3 * WSZ  (bf16)
    short* Qb = Wt + 3 * WSZ;    // Q  [B,H,S,D] bf16
    short* Kb = Qb + QSZ;        // K  [B,H,S,D] bf16
    short* Vtb = Kb + QSZ;       // Vt [B,H,D,S] bf16
    // ws total: 3*WSZ + 3*QSZ shorts = 41.3 MB
    // Xb (bf16 X, 12.6 MB) lives in d_out (25 MB fp32) — consumed by qkv_gemm
    // before band_attn overwrites d_out at the end of the stream.
    short* Xb = (short*)d_out;

    prep<<<dim3(3072 + 3 * 576, 1, 1), 256, 0, stream>>>(hidden, Wq, Wk, Wv, Xb, Wt);

    qkv_gemm<<<dim3(128, 12, 3), 64, 0, stream>>>(Xb, Wt, bq, bk, bv, Qb, Kb, Vtb);

    band_attn<<<dim3(HH * BB, SS / 128, 1), 256, 0, stream>>>(Qb, Kb, Vtb, out);
}

// Round 9
// 181.257 us; speedup vs baseline: 1.0853x; 1.0853x over previous
//
#include <hip/hip_runtime.h>

#define BB 2
#define SS 4096
#define EE 768
#define HH 12
#define DD 64
#define WW 256

typedef __attribute__((ext_vector_type(8))) short short8;
typedef __attribute__((ext_vector_type(4))) short short4v;
typedef __attribute__((ext_vector_type(4))) float floatx4;

#define MFMA16(a, b, c) __builtin_amdgcn_mfma_f32_16x16x32_bf16(a, b, c, 0, 0, 0)

__device__ __forceinline__ float bf2f(short x) {
    union { unsigned u; float f; } v;
    v.u = ((unsigned)(unsigned short)x) << 16;
    return v.f;
}

__device__ __forceinline__ short f2bf(float x) {
    union { float f; unsigned u; } v;
    v.f = x;
    unsigned r = v.u + 0x7fffu + ((v.u >> 16) & 1u);  // RNE
    return (short)(r >> 16);
}

__device__ __forceinline__ int imin(int a, int b) { return a < b ? a : b; }
__device__ __forceinline__ int imax(int a, int b) { return a > b ? a : b; }

// async global->LDS, 16B per lane; LDS dest must be wave-uniform-base + lane*16
__device__ __forceinline__ void gload_lds16(const short* g, short* l) {
    __builtin_amdgcn_global_load_lds(
        (const __attribute__((address_space(1))) unsigned*)g,
        (__attribute__((address_space(3))) unsigned*)l, 16, 0, 0);
}

// Fused prep: blocks [0,3072) convert X fp32->bf16 (8 el/thread);
// blocks [3072,4800) transpose the three 768x768 weights to bf16 Wt[z][n][k].
__global__ __launch_bounds__(256) void prep(
    const float* __restrict__ hidden, const float* __restrict__ W0,
    const float* __restrict__ W1, const float* __restrict__ W2,
    short* __restrict__ Xb, short* __restrict__ Wt) {
    __shared__ short t[32][33];
    int bid = blockIdx.x;
    if (bid < 3072) {
        int i = bid * 256 + threadIdx.x;
        const floatx4* src = (const floatx4*)(hidden + (size_t)i * 8);
        floatx4 f0 = src[0], f1 = src[1];
        short8 s8;
#pragma unroll
        for (int j = 0; j < 4; j++) { s8[j] = f2bf(f0[j]); s8[j + 4] = f2bf(f1[j]); }
        *(short8*)(Xb + (size_t)i * 8) = s8;
    } else {
        int tmp = bid - 3072;
        int z = tmp / 576, r = tmp % 576;
        int bx = r % 24, by = r / 24;
        const float* in = (z == 0) ? W0 : (z == 1) ? W1 : W2;
        short* op = Wt + (size_t)z * EE * EE;
        int tx = threadIdx.x & 31, ty = threadIdx.x >> 5;  // 32 x 8
        int x = bx * 32 + tx, y0 = by * 32;
        for (int j = 0; j < 32; j += 8) t[ty + j][tx] = f2bf(in[(size_t)(y0 + ty + j) * EE + x]);
        __syncthreads();
        int x2 = y0 + tx, y2 = bx * 32;
        for (int j = 0; j < 32; j += 8) op[(size_t)(y2 + ty + j) * EE + x2] = t[tx][ty + j];
    }
}

// C = Xb * W^T(+bias), Xb bf16:[8192][768], Wt bf16:[3][768(n)][768(k)]
// z=0: Q*(1/8) -> [B,H,S,D];  z=1: K -> [B,H,S,D];  z=2: V -> [B,H,D,S]
// R5 structure (BK=32, 128x128 tile, unpadded LDS, global_load_lds w16):
// measured 62.2-62.5 us. BK=64+swizzle and 64x64 wave-tile variants both
// regressed (R6: conflicts were hidden latency; R8: worse staging:MFMA ratio).
__global__ __launch_bounds__(256) void qkv_gemm(
    const short* __restrict__ Xb, const short* __restrict__ Wt,
    const float* __restrict__ Bq, const float* __restrict__ Bk, const float* __restrict__ Bv,
    short* __restrict__ Qo, short* __restrict__ Ko, short* __restrict__ Vto) {
    int z = blockIdx.z;
    const short* Wz = Wt + (size_t)z * EE * EE;
    const float* bias = (z == 0) ? Bq : (z == 1) ? Bk : Bv;

    __shared__ __align__(16) short As[128 * 32];
    __shared__ __align__(16) short Bs[128 * 32];
    int tid = threadIdx.x;
    int m0 = blockIdx.x * 128, n0 = blockIdx.y * 128;
    int wave = tid >> 6, lane = tid & 63, lquad = lane >> 4, lrow = lane & 15;
    int wm = (wave & 1) * 64, wn = (wave >> 1) * 64;

    floatx4 acc[4][4] = {};

    // staging chunks: c = j*256 + tid; row = c>>2, col = (c&3)*8 shorts
    int c0 = tid, c1 = 256 + tid;
    int r0s = c0 >> 2, c0s = (c0 & 3) * 8;
    int r1s = c1 >> 2, c1s = (c1 & 3) * 8;

    for (int k0 = 0; k0 < EE; k0 += 32) {
        gload_lds16(&Xb[(size_t)(m0 + r0s) * EE + k0 + c0s], &As[c0 * 8]);
        gload_lds16(&Wz[(size_t)(n0 + r0s) * EE + k0 + c0s], &Bs[c0 * 8]);
        gload_lds16(&Xb[(size_t)(m0 + r1s) * EE + k0 + c1s], &As[c1 * 8]);
        gload_lds16(&Wz[(size_t)(n0 + r1s) * EE + k0 + c1s], &Bs[c1 * 8]);
        __syncthreads();
        short8 af[4], bfv[4];
#pragma unroll
        for (int mt = 0; mt < 4; mt++)
            af[mt] = *(short8*)&As[(wm + mt * 16 + lrow) * 32 + lquad * 8];
#pragma unroll
        for (int nt = 0; nt < 4; nt++)
            bfv[nt] = *(short8*)&Bs[(wn + nt * 16 + lrow) * 32 + lquad * 8];
#pragma unroll
        for (int mt = 0; mt < 4; mt++)
#pragma unroll
            for (int nt = 0; nt < 4; nt++)
                acc[mt][nt] = MFMA16(af[mt], bfv[nt], acc[mt][nt]);
        __syncthreads();
    }

    if (z == 2) {
        // V, stored transposed: Vt[b,h,d,s]
        for (int nt = 0; nt < 4; nt++) {
            int gn = n0 + wn + nt * 16 + lrow;
            float bv = bias[gn];
            int h = gn >> 6, d = gn & 63;
            for (int mt = 0; mt < 4; mt++) {
                int gm0 = m0 + wm + mt * 16 + lquad * 4;  // multiple of 4
                int b = gm0 >> 12, s = gm0 & (SS - 1);
                short4v pk;
                for (int r = 0; r < 4; r++) pk[r] = f2bf(acc[mt][nt][r] + bv);
                *(short4v*)&Vto[(((size_t)(b * HH + h)) * DD + d) * SS + s] = pk;
            }
        }
    } else {
        short* out = (z == 0) ? Qo : Ko;
        float scale = (z == 0) ? 0.125f : 1.0f;
        for (int nt = 0; nt < 4; nt++) {
            int gn = n0 + wn + nt * 16 + lrow;
            float bv = bias[gn];
            int h = gn >> 6, d = gn & 63;
            for (int mt = 0; mt < 4; mt++) {
                int gmb = m0 + wm + mt * 16 + lquad * 4;
                for (int r = 0; r < 4; r++) {
                    int gm = gmb + r;
                    int b = gm >> 12, s = gm & (SS - 1);
                    float v = (acc[mt][nt][r] + bv) * scale;
                    out[(((size_t)(b * HH + h)) * SS + s) * DD + d] = f2bf(v);
                }
            }
        }
    }
}

// Sliding-window attention v4: 128 queries/block (4 waves x 32 queries),
// double-buffered K/V staging (1 barrier/tile, loads overlap compute) and a
// wave-uniform interior-tile fast path that skips the per-pair band mask
// (7 of 9 tiles per wave are fully in-band). S^T = K*Q^T trick as v3.
// Q,K bf16 [B,H,S,D]; Vt bf16 [B,H,D,S]; out fp32 [B,S,E].
__global__ __launch_bounds__(256) void band_attn(
    const short* __restrict__ Q, const short* __restrict__ K,
    const short* __restrict__ Vt, float* __restrict__ out) {
    int hb = blockIdx.x;  // 0..23 -> same-head chunks land on the same XCD
    int h = hb % HH, b = hb / HH;
    int chunk = blockIdx.y;  // 0..31, 128 queries
    int tid = threadIdx.x;
    int wave = tid >> 6, lane = tid & 63, lquad = lane >> 4, lrow = lane & 15;
    int qbase = chunk * 128 + wave * 32;  // this wave's 32 queries

    const short* Qh = Q + ((size_t)(b * HH + h)) * SS * DD;
    const short* Kh = K + ((size_t)(b * HH + h)) * SS * DD;
    const short* Vh = Vt + ((size_t)(b * HH + h)) * DD * SS;

    __shared__ __align__(16) short Ks[2][64 * 72];  // [key][d], double-buffered
    __shared__ __align__(16) short Vs[2][64 * 72];  // [d][key], double-buffered
    __shared__ __align__(16) short Ps[4][16 * 72];  // per wave: [q][key]
    short* Pw = &Ps[wave][0];

    // Persistent Q B-fragments for 2 m-tiles: B[n=query=lrow][k=d=lquad*8+j]
    short8 qf[2][2];
#pragma unroll
    for (int m = 0; m < 2; m++)
#pragma unroll
        for (int hh = 0; hh < 2; hh++)
            qf[m][hh] = *(const short8*)&Qh[(size_t)(qbase + m * 16 + lrow) * DD + hh * 32 + lquad * 8];

    floatx4 o[2][4] = {};
    float ls[2] = {0.0f, 0.0f};

    int kwin = chunk * 128 - WW;  // block's key-window start (10 tiles of 64)
    int srow = tid >> 3;          // 0..31
    int scol = (tid & 7) * 8;     // 0..56
    int tlo = wave >> 1;          // wave active on tiles [tlo, tlo+9)

    short8 kreg[2], vreg[2];
    auto loadTile = [&](int t) {
        int ks0 = kwin + t * 64;
#pragma unroll
        for (int i = 0; i < 2; i++) {
            int r = srow + i * 32;
            int gk = imin(imax(ks0 + r, 0), SS - 1);
            kreg[i] = *(const short8*)&Kh[(size_t)gk * DD + scol];
            int gv = imin(imax(ks0 + scol, 0), SS - 8);
            vreg[i] = *(const short8*)&Vh[(size_t)r * SS + gv];
        }
    };
    auto storeTile = [&](int buf) {
#pragma unroll
        for (int i = 0; i < 2; i++) {
            int r = srow + i * 32;
            *(short8*)&Ks[buf][r * 72 + scol] = kreg[i];
            *(short8*)&Vs[buf][r * 72 + scol] = vreg[i];
        }
    };

    loadTile(0);
    storeTile(0);
    __syncthreads();

    for (int t = 0; t < 10; t++) {
        int buf = t & 1;
        if (t < 9) loadTile(t + 1);  // in flight during this tile's compute

        if ((unsigned)(t - tlo) < 9u) {  // this wave's 544-key window
            int ks0 = kwin + t * 64;
            short8 kf[4][2], vf[4][2];
#pragma unroll
            for (int kt = 0; kt < 4; kt++)
#pragma unroll
                for (int hh = 0; hh < 2; hh++)
                    kf[kt][hh] = *(short8*)&Ks[buf][(kt * 16 + lrow) * 72 + hh * 32 + lquad * 8];
#pragma unroll
            for (int nt = 0; nt < 4; nt++)
#pragma unroll
                for (int hh = 0; hh < 2; hh++)
                    vf[nt][hh] = *(short8*)&Vs[buf][(nt * 16 + lrow) * 72 + hh * 32 + lquad * 8];

            int d0 = ks0 - qbase;
            bool interior = (d0 >= -225) && (d0 <= 193) && (ks0 >= 0) && (ks0 <= SS - 64);

#pragma unroll
            for (int m = 0; m < 2; m++) {
                int q = qbase + m * 16 + lrow;  // this lane's query (S^T: col = lane&15)
                floatx4 s[4];
#pragma unroll
                for (int kt = 0; kt < 4; kt++) {
                    floatx4 zz = {};
                    s[kt] = MFMA16(kf[kt][0], qf[m][0], zz);
                    s[kt] = MFMA16(kf[kt][1], qf[m][1], s[kt]);
                }
                float lacc = 0.0f;
                if (interior) {
#pragma unroll
                    for (int kt = 0; kt < 4; kt++) {
                        short4v pk;
#pragma unroll
                        for (int r = 0; r < 4; r++) {
                            float p = __expf(s[kt][r]);
                            pk[r] = f2bf(p);
                            lacc += bf2f(pk[r]);
                        }
                        *(short4v*)&Pw[lrow * 72 + kt * 16 + lquad * 4] = pk;
                    }
                } else {
#pragma unroll
                    for (int kt = 0; kt < 4; kt++) {
                        short4v pk;
#pragma unroll
                        for (int r = 0; r < 4; r++) {
                            int key = ks0 + kt * 16 + lquad * 4 + r;
                            bool valid = ((unsigned)(key - q + WW) <= 2u * WW) && ((unsigned)key < SS);
                            float p = valid ? __expf(s[kt][r]) : 0.0f;
                            pk[r] = f2bf(p);
                            lacc += bf2f(pk[r]);
                        }
                        *(short4v*)&Pw[lrow * 72 + kt * 16 + lquad * 4] = pk;
                    }
                }
                ls[m] += lacc;
                asm volatile("" ::: "memory");  // order P write->read (same-wave DS is in-order)
                short8 ap0 = *(short8*)&Pw[lrow * 72 + lquad * 8];
                short8 ap1 = *(short8*)&Pw[lrow * 72 + 32 + lquad * 8];
#pragma unroll
                for (int nt = 0; nt < 4; nt++) {
                    o[m][nt] = MFMA16(ap0, vf[nt][0], o[m][nt]);
                    o[m][nt] = MFMA16(ap1, vf[nt][1], o[m][nt]);
                }
            }
        }

        if (t < 9) storeTile(buf ^ 1);  // tile t+1 into the other buffer
        __syncthreads();
    }

    // ls[m]: per-lane partials over this lane's quad; reduce across quads
#pragma unroll
    for (int m = 0; m < 2; m++) {
        ls[m] += __shfl_xor(ls[m], 16, 64);
        ls[m] += __shfl_xor(ls[m], 32, 64);
        ls[m] = 1.0f / ls[m];  // lane L holds 1/ls for query (L&15)
    }

#pragma unroll
    for (int m = 0; m < 2; m++) {
#pragma unroll
        for (int r = 0; r < 4; r++) {
            float linv = __shfl(ls[m], lquad * 4 + r, 64);
            int s = qbase + m * 16 + lquad * 4 + r;
#pragma unroll
            for (int nt = 0; nt < 4; nt++)
                out[((size_t)b * SS + s) * EE + h * DD + nt * 16 + lrow] = o[m][nt][r] * linv;
        }
    }
}

extern "C" void kernel_launch(void* const* d_in, const int* in_sizes, int n_in,
                              void* d_out, int out_size, void* d_ws, size_t ws_size,
                              hipStream_t stream) {
    const float* hidden = (const float*)d_in[0];
    const float* Wq = (const float*)d_in[1];
    const float* bq = (const float*)d_in[2];
    const float* Wk = (const float*)d_in[3];
    const float* bk = (const float*)d_in[4];
    const float* Wv = (const float*)d_in[5];
    const float* bv = (const float*)d_in[6];
    float* out = (float*)d_out;

    short* ws = (short*)d_ws;
    const size_t WSZ = (size_t)EE * EE;            // 589824
    const size_t QSZ = (size_t)BB * HH * SS * DD;  // 6291456
    short* Wt = ws;              // 3 * WSZ  (bf16)
    short* Qb = Wt + 3 * WSZ;    // Q  [B,H,S,D] bf16
    short* Kb = Qb + QSZ;        // K  [B,H,S,D] bf16
    short* Vtb = Kb + QSZ;       // Vt [B,H,D,S] bf16
    // ws total: 3*WSZ + 3*QSZ shorts = 41.3 MB
    // Xb (bf16 X, 12.6 MB) lives in d_out (25 MB fp32) — consumed by qkv_gemm
    // before band_attn overwrites d_out at the end of the stream.
    short* Xb = (short*)d_out;

    prep<<<dim3(3072 + 3 * 576, 1, 1), 256, 0, stream>>>(hidden, Wq, Wk, Wv, Xb, Wt);

    qkv_gemm<<<dim3(64, 6, 3), 256, 0, stream>>>(Xb, Wt, bq, bk, bv, Qb, Kb, Vtb);

    band_attn<<<dim3(HH * BB, SS / 128, 1), 256, 0, stream>>>(Qb, Kb, Vtb, out);
}